// Round 8
// baseline (166.617 us; speedup 1.0000x reference)
//
#include <hip/hip_runtime.h>
#include <stdint.h>

// MPS chain contraction, B=32768, L=256, D=16.
// R15: R12 base (best measured, 58.8us) + direct coefficient loads +
//      fused dual-chain MFMA interleave. NO asm/sched_barrier/setprio:
//      R13 (intrinsic pins, 71us) and R14 (asm pins, 75us) both lost to
//      the compiler's own schedule (R12 58.8) -> stop fighting it.
//   Budget at 58.8us/SIMD: VALU-issue ~26us, MFMA-pipe ~16us (19.4cy per
//   16x16x32 per SIMD), ~19us idle. Levers: cut VALU/DS work, add ILP.
//   (1) per-lane phi coefficient loads (float2 from own row; L1 broadcast
//       across the 4 g-lanes) replace 16 ds_bpermute + window machinery.
//   (2) pair_step2 interleaves the 2 chains' 16 MFMAs explicitly.
//   (3) peeled final chunk removes all clamp logic from the hot loop.

typedef short  bf16x8 __attribute__((ext_vector_type(8)));
typedef float  f32x4  __attribute__((ext_vector_type(4)));
typedef int    i32x4  __attribute__((ext_vector_type(4)));
typedef unsigned int u32;

#define NPF 64
#define NPB 63
#define BWD_OFF (NPF*4*64)   // i32x4 units

#define PACK_HI(hi, lo) ((int)__builtin_amdgcn_perm((u32)(hi), (u32)(lo), 0x07060302u))

__device__ __forceinline__ u32 rne_bump(u32 u){ return u + 0x7FFFu + ((u >> 16) & 1u); }

// Pair-fragment table: blocks 0..63 fwd (j=bid), 64..126 bwd (j=bid-64).
// fwd: G[m][cq] = sum_r Ca[cq][p][r]*Cb[r][q][m],  Ca=cm[2j], Cb=cm[2j+1]
// bwd: G[m][cq] = sum_r Ca[m][p][r]*Cb[r][q][cq],  Ca=cm[252-2j], Cb=cm[253-2j]
// lane (m=lane&15, g=lane>>4) packs cols 4g..4g+3 hi (dw0,1) and lo (dw2,3).
__global__ void build_pair_frags(const float* __restrict__ cm, i32x4* __restrict__ ws)
{
  __shared__ float Ca[512], Cb[512];   // [x][p][y] = cm[t][x][p][y]
  const int bid = blockIdx.x;
  const bool fwd = bid < NPF;
  const int j  = fwd ? bid : bid - NPF;
  const int ta = fwd ? 2*j     : 252 - 2*j;
  const int tb = fwd ? 2*j + 1 : 253 - 2*j;
  {
    const float* A = cm + ta*512;
    const float* B = cm + tb*512;
    for (int i = threadIdx.x; i < 512; i += 256){ Ca[i] = A[i]; Cb[i] = B[i]; }
  }
  __syncthreads();
  const int f    = threadIdx.x >> 6;    // combo p*2+q
  const int lane = threadIdx.x & 63;
  const int m    = lane & 15;
  const int g    = lane >> 4;
  const int p    = f >> 1, q = f & 1;
  u32 hi[4], lo[4];
  #pragma unroll
  for (int x = 0; x < 4; ++x){
    const int cq = 4*g + x;
    float acc = 0.f;
    #pragma unroll
    for (int r = 0; r < 16; ++r){
      const float a = fwd ? Ca[cq*32 + p*16 + r] : Ca[m*32 + p*16 + r];
      const float b = fwd ? Cb[r*32 + q*16 + m]  : Cb[r*32 + q*16 + cq];
      acc = fmaf(a, b, acc);
    }
    const u32 u  = __float_as_uint(acc);
    const u32 aa = rne_bump(u);
    const float hf = __uint_as_float(aa & 0xFFFF0000u);
    const u32 bb = rne_bump(__float_as_uint(acc - hf));
    hi[x] = aa >> 16; lo[x] = bb >> 16;
  }
  i32x4 w;
  w[0] = (int)(hi[0] | (hi[1] << 16));
  w[1] = (int)(hi[2] | (hi[3] << 16));
  w[2] = (int)(lo[0] | (lo[1] << 16));
  w[3] = (int)(lo[2] | (lo[3] << 16));
  ws[(fwd ? 0 : BWD_OFF) + (j*4 + f)*64 + lane] = w;
}

__device__ __forceinline__ void make_bfrag(const float (&v)[4], i32x4 &bfr)
{
  const u32 u0 = __float_as_uint(v[0]), u1 = __float_as_uint(v[1]);
  const u32 u2 = __float_as_uint(v[2]), u3 = __float_as_uint(v[3]);
  const float l0 = v[0] - __uint_as_float(u0 & 0xFFFF0000u);
  const float l1 = v[1] - __uint_as_float(u1 & 0xFFFF0000u);
  const float l2 = v[2] - __uint_as_float(u2 & 0xFFFF0000u);
  const float l3 = v[3] - __uint_as_float(u3 & 0xFFFF0000u);
  bfr[0] = PACK_HI(u1, u0);
  bfr[1] = PACK_HI(u3, u2);
  bfr[2] = PACK_HI(__float_as_uint(l1), __float_as_uint(l0));
  bfr[3] = PACK_HI(__float_as_uint(l3), __float_as_uint(l2));
}

#define MFMA_(G,Bv,Cv) __builtin_amdgcn_mfma_f32_16x16x32_bf16(__builtin_bit_cast(bf16x8,(G)), (Bv), (Cv), 0,0,0)

// Two chains fused: MFMAs interleaved A/B so the matrix pipe always has an
// independent instruction; VALU tails of one chain hide under the other.
__device__ __forceinline__ void pair_step2(
    const i32x4 &G0, const i32x4 &G1, const i32x4 &G2, const i32x4 &G3,
    float2 cAa, float2 cBa, float2 cAb, float2 cBb,
    float (&vA)[4], float (&vB)[4], i32x4 &bA, i32x4 &bB)
{
  i32x4 sA; sA[0]=bA[2]; sA[1]=bA[3]; sA[2]=bA[0]; sA[3]=bA[1];
  i32x4 sB; sB[0]=bB[2]; sB[1]=bB[3]; sB[2]=bB[0]; sB[3]=bB[1];
  const bf16x8 hA = __builtin_bit_cast(bf16x8,bA), wA = __builtin_bit_cast(bf16x8,sA);
  const bf16x8 hB = __builtin_bit_cast(bf16x8,bB), wB = __builtin_bit_cast(bf16x8,sB);
  const f32x4 z = {0.f,0.f,0.f,0.f};
  f32x4 a0A = MFMA_(G0,hA,z);   f32x4 a0B = MFMA_(G0,hB,z);
  a0A = MFMA_(G0,wA,a0A);       a0B = MFMA_(G0,wB,a0B);
  f32x4 a1A = MFMA_(G1,hA,z);   f32x4 a1B = MFMA_(G1,hB,z);
  a1A = MFMA_(G1,wA,a1A);       a1B = MFMA_(G1,wB,a1B);
  f32x4 a2A = MFMA_(G2,hA,z);   f32x4 a2B = MFMA_(G2,hB,z);
  a2A = MFMA_(G2,wA,a2A);       a2B = MFMA_(G2,wB,a2B);
  f32x4 a3A = MFMA_(G3,hA,z);   f32x4 a3B = MFMA_(G3,hB,z);
  a3A = MFMA_(G3,wA,a3A);       a3B = MFMA_(G3,wB,a3B);
  const float c00A=cAa.x*cBa.x, c01A=cAa.x*cBa.y, c10A=cAa.y*cBa.x, c11A=cAa.y*cBa.y;
  const float c00B=cAb.x*cBb.x, c01B=cAb.x*cBb.y, c10B=cAb.y*cBb.x, c11B=cAb.y*cBb.y;
  #pragma unroll
  for (int i = 0; i < 4; ++i){
    vA[i] = c00A*a0A[i] + c01A*a1A[i] + c10A*a2A[i] + c11A*a3A[i];
    vB[i] = c00B*a0B[i] + c01B*a1B[i] + c10B*a2B[i] + c11B*a3B[i];
  }
  make_bfrag(vA, bA);
  make_bfrag(vB, bB);
}

__global__ __launch_bounds__(256, 2) void mps_chain(
  const float* __restrict__ phi,
  const float* __restrict__ core_first,
  const float* __restrict__ core_last,
  const float* __restrict__ bias,
  const i32x4* __restrict__ ws,
  float* __restrict__ out)
{
  const int lane = threadIdx.x & 63;
  const int wv   = threadIdx.x >> 6;
  const int n    = lane & 15;            // sample column within a group
  const int g    = lane >> 4;            // matrix row group
  const bool isFwd = (wv < 2);
  const int dirIdx = isFwd ? 0 : 1;
  const int sb   = blockIdx.x * 64 + (wv & 1) * 32;   // wave: 2 chains x 16

  __shared__ float red[128*20];          // epilogue reduction only (10 KB)

  const i32x4* wsD    = isFwd ? ws : (ws + BWD_OFF);
  const int    maxPr  = isFwd ? NPF - 1 : NPB - 1;
  const i32x4* wsLane = wsD + lane;      // + pr*256 + f*64 selects (pair, combo)

  // per-chain sample rows (all 4 g-lanes of a column read the same address)
  const float*  row0 = phi + (size_t)(sb + n) * 512;
  const float*  row1 = phi + (size_t)(sb + 16 + n) * 512;
  const float2* c20  = (const float2*)row0;   // float2 index = phi[t] pair
  const float2* c21  = (const float2*)row1;

  // chunk c coefficients (float2 index):
  //   even pair (2c):  cA = c2[uB + st*c], cB = c2[uB + st*c + 1]
  //   odd  pair (2c+1):cA = c2[vB + st*c], cB = c2[vB + st*c + 1]
  const int uB = isFwd ? 1 : 253;
  const int vB = isFwd ? 3 : 251;
  const int st = isFwd ? 4 : -4;

  // ---- chain state ----
  float vA[4], vBv[4];
  i32x4 bA, bB;
  {
    if (isFwd){
      const float2 p0 = *(const float2*)row0;
      const float2 p1 = *(const float2*)row1;
      #pragma unroll
      for (int r = 0; r < 4; ++r){
        const int rr = g*4 + r;
        vA[r]  = p0.x * core_first[rr] + p0.y * core_first[16 + rr];
        vBv[r] = p1.x * core_first[rr] + p1.y * core_first[16 + rr];
      }
    } else {
      const float2 p0 = *(const float2*)(row0 + 510);
      const float2 p1 = *(const float2*)(row1 + 510);
      #pragma unroll
      for (int r = 0; r < 4; ++r){
        const int rr = g*4 + r;
        vA[r]  = p0.x * core_last[2*rr] + p0.y * core_last[2*rr + 1];
        vBv[r] = p1.x * core_last[2*rr] + p1.y * core_last[2*rr + 1];
      }
    }
    make_bfrag(vA, bA);
    make_bfrag(vBv, bB);
  }

  // ---- register prefetch state: pairs 2c, 2c+1 + chunk coefficients ----
  i32x4 A0,A1,A2,A3, B0,B1,B2,B3;
  float2 eA0, eB0, eA1, eB1;   // even-pair coeffs, chains 0/1
  float2 oA0, oB0, oA1, oB1;   // odd-pair coeffs, chains 0/1

  { const i32x4* s = wsLane;        A0=s[0]; A1=s[64]; A2=s[128]; A3=s[192]; }
  { const i32x4* s = wsLane + 256;  B0=s[0]; B1=s[64]; B2=s[128]; B3=s[192]; }
  eA0 = c20[uB];     eB0 = c20[uB + 1];
  eA1 = c21[uB];     eB1 = c21[uB + 1];
  oA0 = c20[vB];     oB0 = c20[vB + 1];
  oA1 = c21[vB];     oB1 = c21[vB + 1];

  #pragma unroll 1
  for (int c = 0; c < 31; ++c){
    // ---- prefetch chunk c+1 (pairs 2c+2, 2c+3; coefficients) ----
    i32x4 nA0,nA1,nA2,nA3, nB0,nB1,nB2,nB3;
    { const i32x4* s = wsLane + (2*c + 2) * 256;           // <= 62, in range both dirs
      nA0=s[0]; nA1=s[64]; nA2=s[128]; nA3=s[192]; }
    { int j3 = 2*c + 3; if (j3 > maxPr) j3 = maxPr;        // bwd c=30: clamp 63->62
      const i32x4* s = wsLane + j3 * 256;
      nB0=s[0]; nB1=s[64]; nB2=s[128]; nB3=s[192]; }
    const int u1 = uB + st*(c+1), v1 = vB + st*(c+1);
    const float2 neA0 = c20[u1], neB0 = c20[u1+1], neA1 = c21[u1], neB1 = c21[u1+1];
    const float2 noA0 = c20[v1], noB0 = c20[v1+1], noA1 = c21[v1], noB1 = c21[v1+1];

    // ---- compute chunk c ----
    pair_step2(A0,A1,A2,A3, eA0,eB0, eA1,eB1, vA,vBv, bA,bB);
    pair_step2(B0,B1,B2,B3, oA0,oB0, oA1,oB1, vA,vBv, bA,bB);

    // ---- rotate ----
    A0=nA0; A1=nA1; A2=nA2; A3=nA3;  B0=nB0; B1=nB1; B2=nB2; B3=nB3;
    eA0=neA0; eB0=neB0; eA1=neA1; eB1=neB1;
    oA0=noA0; oB0=noB0; oA1=noA1; oB1=noB1;
  }

  // ---- peeled chunk 31: pair 62 always; pair 63 fwd only ----
  pair_step2(A0,A1,A2,A3, eA0,eB0, eA1,eB1, vA,vBv, bA,bB);
  if (isFwd)
    pair_step2(B0,B1,B2,B3, oA0,oB0, oA1,oB1, vA,vBv, bA,bB);

  // ---- epilogue: cross-wave reduction ----
  *(float4*)&red[(dirIdx*64 + (wv & 1)*32 + n)*20 + 4*g] =
      make_float4(vA[0], vA[1], vA[2], vA[3]);
  *(float4*)&red[(dirIdx*64 + (wv & 1)*32 + 16 + n)*20 + 4*g] =
      make_float4(vBv[0], vBv[1], vBv[2], vBv[3]);
  __syncthreads();
  if (threadIdx.x < 64){
    const int s = threadIdx.x;
    float acc = bias[0];
    #pragma unroll
    for (int qq = 0; qq < 16; ++qq)
      acc += red[s*20 + qq] * red[(64 + s)*20 + qq];
    out[blockIdx.x*64 + s] = acc;
  }
}

extern "C" void kernel_launch(void* const* d_in, const int* in_sizes, int n_in,
                              void* d_out, int out_size, void* d_ws, size_t ws_size,
                              hipStream_t stream)
{
  const float* phi  = (const float*)d_in[0];  // [32768,256,2]
  const float* cf   = (const float*)d_in[1];  // [2,16]
  const float* cm   = (const float*)d_in[2];  // [254,16,2,16]
  const float* cl   = (const float*)d_in[3];  // [16,2]
  const float* bias = (const float*)d_in[4];  // scalar
  i32x4* ws = (i32x4*)d_ws;                   // (64+63)*4*64*16B = 508 KB

  build_pair_frags<<<NPF + NPB, 256, 0, stream>>>(cm, ws);
  mps_chain<<<512, 256, 0, stream>>>(phi, cf, cl, bias, ws, (float*)d_out);
}

// Round 9
// 148.805 us; speedup vs baseline: 1.1197x; 1.1197x over previous
//
#include <hip/hip_runtime.h>
#include <stdint.h>

// MPS chain contraction, B=32768, L=256, D=16.
// R16: R12 (best measured, 58.8us) with ONE change: the bpermute
//   coefficient path is replaced by direct per-chain float2 loads
//   (mapping verified correct by R15's pass). Removes per chunk:
//   16 ds_bpermute + lgkm waits + f32x4 window load/rotate/prefetch
//   (~25 VALU/DS ops). Clamps peeled out of the hot loop (R15-verified).
//   NO rotate carousel, NO sched_barrier, NO setprio, NO manual waits --
//   R8/R13/R14/R15 all showed manual scheduling loses to the compiler.
//   Clean A/B vs R12: if ~59us null => latency-bound confirmed, next
//   round = 32x32x16 batch decomposition.

typedef short  bf16x8 __attribute__((ext_vector_type(8)));
typedef float  f32x4  __attribute__((ext_vector_type(4)));
typedef int    i32x4  __attribute__((ext_vector_type(4)));
typedef unsigned int u32;

#define NPF 64
#define NPB 63
#define BWD_OFF (NPF*4*64)   // i32x4 units

#define PACK_HI(hi, lo) ((int)__builtin_amdgcn_perm((u32)(hi), (u32)(lo), 0x07060302u))

__device__ __forceinline__ u32 rne_bump(u32 u){ return u + 0x7FFFu + ((u >> 16) & 1u); }

// Pair-fragment table: blocks 0..63 fwd (j=bid), 64..126 bwd (j=bid-64).
// fwd: G[m][cq] = sum_r Ca[cq][p][r]*Cb[r][q][m],  Ca=cm[2j], Cb=cm[2j+1]
// bwd: G[m][cq] = sum_r Ca[m][p][r]*Cb[r][q][cq],  Ca=cm[252-2j], Cb=cm[253-2j]
// lane (m=lane&15, g=lane>>4) packs cols 4g..4g+3 hi (dw0,1) and lo (dw2,3).
__global__ void build_pair_frags(const float* __restrict__ cm, i32x4* __restrict__ ws)
{
  __shared__ float Ca[512], Cb[512];   // [x][p][y] = cm[t][x][p][y]
  const int bid = blockIdx.x;
  const bool fwd = bid < NPF;
  const int j  = fwd ? bid : bid - NPF;
  const int ta = fwd ? 2*j     : 252 - 2*j;
  const int tb = fwd ? 2*j + 1 : 253 - 2*j;
  {
    const float* A = cm + ta*512;
    const float* B = cm + tb*512;
    for (int i = threadIdx.x; i < 512; i += 256){ Ca[i] = A[i]; Cb[i] = B[i]; }
  }
  __syncthreads();
  const int f    = threadIdx.x >> 6;    // combo p*2+q
  const int lane = threadIdx.x & 63;
  const int m    = lane & 15;
  const int g    = lane >> 4;
  const int p    = f >> 1, q = f & 1;
  u32 hi[4], lo[4];
  #pragma unroll
  for (int x = 0; x < 4; ++x){
    const int cq = 4*g + x;
    float acc = 0.f;
    #pragma unroll
    for (int r = 0; r < 16; ++r){
      const float a = fwd ? Ca[cq*32 + p*16 + r] : Ca[m*32 + p*16 + r];
      const float b = fwd ? Cb[r*32 + q*16 + m]  : Cb[r*32 + q*16 + cq];
      acc = fmaf(a, b, acc);
    }
    const u32 u  = __float_as_uint(acc);
    const u32 aa = rne_bump(u);
    const float hf = __uint_as_float(aa & 0xFFFF0000u);
    const u32 bb = rne_bump(__float_as_uint(acc - hf));
    hi[x] = aa >> 16; lo[x] = bb >> 16;
  }
  i32x4 w;
  w[0] = (int)(hi[0] | (hi[1] << 16));
  w[1] = (int)(hi[2] | (hi[3] << 16));
  w[2] = (int)(lo[0] | (lo[1] << 16));
  w[3] = (int)(lo[2] | (lo[3] << 16));
  ws[(fwd ? 0 : BWD_OFF) + (j*4 + f)*64 + lane] = w;
}

__device__ __forceinline__ void make_bfrag(const float (&v)[4], i32x4 &bfr)
{
  const u32 u0 = __float_as_uint(v[0]), u1 = __float_as_uint(v[1]);
  const u32 u2 = __float_as_uint(v[2]), u3 = __float_as_uint(v[3]);
  const float l0 = v[0] - __uint_as_float(u0 & 0xFFFF0000u);
  const float l1 = v[1] - __uint_as_float(u1 & 0xFFFF0000u);
  const float l2 = v[2] - __uint_as_float(u2 & 0xFFFF0000u);
  const float l3 = v[3] - __uint_as_float(u3 & 0xFFFF0000u);
  bfr[0] = PACK_HI(u1, u0);
  bfr[1] = PACK_HI(u3, u2);
  bfr[2] = PACK_HI(__float_as_uint(l1), __float_as_uint(l0));
  bfr[3] = PACK_HI(__float_as_uint(l3), __float_as_uint(l2));
}

__device__ __forceinline__ void pair_step(
    const i32x4 &G0, const i32x4 &G1, const i32x4 &G2, const i32x4 &G3,
    float2 cA, float2 cB, float (&v)[4], i32x4 &bfr)
{
  const float c00 = cA.x*cB.x, c01 = cA.x*cB.y;
  const float c10 = cA.y*cB.x, c11 = cA.y*cB.y;
  i32x4 sw; sw[0]=bfr[2]; sw[1]=bfr[3]; sw[2]=bfr[0]; sw[3]=bfr[1];
  const bf16x8 bh = __builtin_bit_cast(bf16x8, bfr);
  const bf16x8 bs = __builtin_bit_cast(bf16x8, sw);
  const f32x4 z = {0.f,0.f,0.f,0.f};
  f32x4 a00 = __builtin_amdgcn_mfma_f32_16x16x32_bf16(__builtin_bit_cast(bf16x8,G0), bh, z, 0,0,0);
  a00 = __builtin_amdgcn_mfma_f32_16x16x32_bf16(__builtin_bit_cast(bf16x8,G0), bs, a00, 0,0,0);
  f32x4 a01 = __builtin_amdgcn_mfma_f32_16x16x32_bf16(__builtin_bit_cast(bf16x8,G1), bh, z, 0,0,0);
  a01 = __builtin_amdgcn_mfma_f32_16x16x32_bf16(__builtin_bit_cast(bf16x8,G1), bs, a01, 0,0,0);
  f32x4 a10 = __builtin_amdgcn_mfma_f32_16x16x32_bf16(__builtin_bit_cast(bf16x8,G2), bh, z, 0,0,0);
  a10 = __builtin_amdgcn_mfma_f32_16x16x32_bf16(__builtin_bit_cast(bf16x8,G2), bs, a10, 0,0,0);
  f32x4 a11 = __builtin_amdgcn_mfma_f32_16x16x32_bf16(__builtin_bit_cast(bf16x8,G3), bh, z, 0,0,0);
  a11 = __builtin_amdgcn_mfma_f32_16x16x32_bf16(__builtin_bit_cast(bf16x8,G3), bs, a11, 0,0,0);
  #pragma unroll
  for (int i2 = 0; i2 < 4; ++i2)
    v[i2] = c00*a00[i2] + c01*a01[i2] + c10*a10[i2] + c11*a11[i2];
  make_bfrag(v, bfr);
}

__global__ __launch_bounds__(256, 2) void mps_chain(
  const float* __restrict__ phi,
  const float* __restrict__ core_first,
  const float* __restrict__ core_last,
  const float* __restrict__ bias,
  const i32x4* __restrict__ ws,
  float* __restrict__ out)
{
  const int lane = threadIdx.x & 63;
  const int wv   = threadIdx.x >> 6;
  const int n    = lane & 15;            // sample column within a group
  const int g    = lane >> 4;            // matrix row group
  const bool isFwd = (wv < 2);
  const int dirIdx = isFwd ? 0 : 1;
  const int sb   = blockIdx.x * 64 + (wv & 1) * 32;   // wave: 2 chains x 16

  __shared__ float red[128*20];          // epilogue reduction only (10 KB)

  const i32x4* wsD    = isFwd ? ws : (ws + BWD_OFF);
  const i32x4* wsLane = wsD + lane;      // + pr*256 + f*64 selects (pair, combo)

  // per-chain sample rows; float2 index i = phi site i (feat0, feat1)
  const float*  row0 = phi + (size_t)(sb + n) * 512;
  const float*  row1 = phi + (size_t)(sb + 16 + n) * 512;
  const float2* c20  = (const float2*)row0;
  const float2* c21  = (const float2*)row1;

  // chunk-c coefficient indices (verified by R15's pass):
  //   even pair 2c:  sites uB+st*c, uB+st*c+1
  //   odd  pair 2c+1: sites vB+st*c, vB+st*c+1
  const int uB = isFwd ? 1 : 253;
  const int vB = isFwd ? 3 : 251;
  const int st = isFwd ? 4 : -4;

  // ---- chain state: 2 independent chains ----
  float vch[2][4];
  i32x4 bfr[2];
  {
    if (isFwd){
      const float2 p0 = *(const float2*)row0;
      const float2 p1 = *(const float2*)row1;
      #pragma unroll
      for (int r = 0; r < 4; ++r){
        const int rr = g*4 + r;
        vch[0][r] = p0.x * core_first[rr] + p0.y * core_first[16 + rr];
        vch[1][r] = p1.x * core_first[rr] + p1.y * core_first[16 + rr];
      }
    } else {
      const float2 p0 = *(const float2*)(row0 + 510);
      const float2 p1 = *(const float2*)(row1 + 510);
      #pragma unroll
      for (int r = 0; r < 4; ++r){
        const int rr = g*4 + r;
        vch[0][r] = p0.x * core_last[2*rr] + p0.y * core_last[2*rr + 1];
        vch[1][r] = p1.x * core_last[2*rr] + p1.y * core_last[2*rr + 1];
      }
    }
    make_bfrag(vch[0], bfr[0]);
    make_bfrag(vch[1], bfr[1]);
  }

  #pragma unroll 1
  for (int c = 0; c < 31; ++c){
    // frags for pairs 2c, 2c+1 (2c<=60, 2c+1<=61: in range both dirs)
    i32x4 A0,A1,A2,A3, B0,B1,B2,B3;
    { const i32x4* s = wsLane + (2*c    )*256; A0=s[0]; A1=s[64]; A2=s[128]; A3=s[192]; }
    { const i32x4* s = wsLane + (2*c + 1)*256; B0=s[0]; B1=s[64]; B2=s[128]; B3=s[192]; }
    // coefficients: direct loads from own phi rows (L2-hot, induction addrs)
    const int u = uB + st*c, w = vB + st*c;
    const float2 eA0 = c20[u], eB0 = c20[u+1];
    const float2 eA1 = c21[u], eB1 = c21[u+1];
    const float2 oA0 = c20[w], oB0 = c20[w+1];
    const float2 oA1 = c21[w], oB1 = c21[w+1];

    pair_step(A0,A1,A2,A3, eA0,eB0, vch[0], bfr[0]);
    pair_step(A0,A1,A2,A3, eA1,eB1, vch[1], bfr[1]);
    pair_step(B0,B1,B2,B3, oA0,oB0, vch[0], bfr[0]);
    pair_step(B0,B1,B2,B3, oA1,oB1, vch[1], bfr[1]);
  }

  // ---- peeled chunk 31: pair 62 always; pair 63 fwd only ----
  {
    i32x4 A0,A1,A2,A3, B0,B1,B2,B3;
    { const i32x4* s = wsLane + 62*256; A0=s[0]; A1=s[64]; A2=s[128]; A3=s[192]; }
    { const int j3 = isFwd ? 63 : 62;   // bwd: clamp (pair 63 absent)
      const i32x4* s = wsLane + j3*256; B0=s[0]; B1=s[64]; B2=s[128]; B3=s[192]; }
    const int u = uB + st*31, w = vB + st*31;
    const float2 eA0 = c20[u], eB0 = c20[u+1];
    const float2 eA1 = c21[u], eB1 = c21[u+1];
    const float2 oA0 = c20[w], oB0 = c20[w+1];
    const float2 oA1 = c21[w], oB1 = c21[w+1];

    pair_step(A0,A1,A2,A3, eA0,eB0, vch[0], bfr[0]);
    pair_step(A0,A1,A2,A3, eA1,eB1, vch[1], bfr[1]);
    if (isFwd){
      pair_step(B0,B1,B2,B3, oA0,oB0, vch[0], bfr[0]);
      pair_step(B0,B1,B2,B3, oA1,oB1, vch[1], bfr[1]);
    }
  }

  // ---- epilogue: cross-wave reduction ----
  *(float4*)&red[(dirIdx*64 + (wv & 1)*32 + n)*20 + 4*g] =
      make_float4(vch[0][0], vch[0][1], vch[0][2], vch[0][3]);
  *(float4*)&red[(dirIdx*64 + (wv & 1)*32 + 16 + n)*20 + 4*g] =
      make_float4(vch[1][0], vch[1][1], vch[1][2], vch[1][3]);
  __syncthreads();
  if (threadIdx.x < 64){
    const int s = threadIdx.x;
    float acc = bias[0];
    #pragma unroll
    for (int qq = 0; qq < 16; ++qq)
      acc += red[s*20 + qq] * red[(64 + s)*20 + qq];
    out[blockIdx.x*64 + s] = acc;
  }
}

extern "C" void kernel_launch(void* const* d_in, const int* in_sizes, int n_in,
                              void* d_out, int out_size, void* d_ws, size_t ws_size,
                              hipStream_t stream)
{
  const float* phi  = (const float*)d_in[0];  // [32768,256,2]
  const float* cf   = (const float*)d_in[1];  // [2,16]
  const float* cm   = (const float*)d_in[2];  // [254,16,2,16]
  const float* cl   = (const float*)d_in[3];  // [16,2]
  const float* bias = (const float*)d_in[4];  // scalar
  i32x4* ws = (i32x4*)d_ws;                   // (64+63)*4*64*16B = 508 KB

  build_pair_frags<<<NPF + NPB, 256, 0, stream>>>(cm, ws);
  mps_chain<<<512, 256, 0, stream>>>(phi, cf, cl, bias, ws, (float*)d_out);
}